// Round 12
// baseline (355.932 us; speedup 1.0000x reference)
//
#include <hip/hip_runtime.h>
#include <hip/hip_fp16.h>

typedef _Float16 f16x8 __attribute__((ext_vector_type(8)));
typedef float f32x4 __attribute__((ext_vector_type(4)));

#define KSEL0 1372u   // int(2048*0.67)
#define KSEL1 1536u   // int(2048*0.75)
#define KSEL2 1638u   // int(2048*0.80)
#define WSC 16.0f
#define QS   0.1803368801f   // 0.125 * log2(e): scores stored in log2-domain
#define CSH2 11.5416222f     // 8 * log2(e): e = exp2(s' - CSH2) == exp(s - 8)

__device__ __forceinline__ unsigned ou16_of(unsigned hb) {
  return hb ^ ((hb & 0x8000u) ? 0xFFFFu : 0x8000u);
}
__device__ __forceinline__ unsigned ou16_inv(unsigned ou) {
  return (ou & 0x8000u) ? (ou ^ 0x8000u) : (ou ^ 0xFFFFu);
}
__device__ __forceinline__ unsigned pk2(float a, float b) {
  auto h = __builtin_amdgcn_cvt_pkrtz(a, b);
  return __builtin_bit_cast(unsigned, h);
}
__device__ __forceinline__ unsigned shflx(unsigned v, int m) {
  return (unsigned)__shfl_xor((int)v, m, 64);
}
__device__ __forceinline__ float h2f(unsigned bits16) {
  return __half2float(__ushort_as_half((unsigned short)bits16));
}

// inclusive suffix-sum over 64 lanes (u32 add; packed 16-bit fields safe when
// each field's total < 65536 — counts here are <= 2048)
__device__ __forceinline__ unsigned suffix64(unsigned s4, int lane) {
  unsigned p = s4;
  #pragma unroll
  for (int off = 1; off < 64; off <<= 1) {
    int sl = lane + off;
    unsigned t = (unsigned)__shfl((int)p, sl < 64 ? sl : lane, 64);
    p += (sl < 64) ? t : 0u;
  }
  return p;
}
// per-lane bin counts (logical bins 4l..4l+3) + suffix tail -> k-th-largest digit
// returns (digit<<16) | remainder-k
__device__ __forceinline__ unsigned pick_digit(unsigned tail, unsigned hx, unsigned hy,
                                               unsigned hz, unsigned hw_, unsigned k, int lane) {
  unsigned s4 = hx + hy + hz + hw_;
  unsigned a3 = tail - s4;
  unsigned a2 = a3 + hw_;
  unsigned a1 = a2 + hz;
  unsigned a0 = a1 + hy;
  int d = -1; unsigned nk = 0;
  if (a3 < k && a3 + hw_ >= k)      { d = 4*lane+3; nk = k - a3; }
  else if (a2 < k && a2 + hz >= k)  { d = 4*lane+2; nk = k - a2; }
  else if (a1 < k && a1 + hy >= k)  { d = 4*lane+1; nk = k - a1; }
  else if (a0 < k && a0 + hx >= k)  { d = 4*lane+0; nk = k - a0; }
  unsigned long long mb = __ballot(d >= 0);
  int src = __ffsll(mb) - 1;
  unsigned pack = ((unsigned)d << 16) | nk;
  return (unsigned)__shfl((int)pack, src, 64);
}

// ---------- fused prep: K fp32 -> Kh fp16 [bh][s][e]; V fp32 -> Vt fp16 [bh][d][s] ----------
extern "C" __global__ __launch_bounds__(256)
void prep_kv(const float* __restrict__ K, const float* __restrict__ V,
             unsigned short* __restrict__ Kh, unsigned short* __restrict__ Vt) {
  if (blockIdx.x < 2048) {
    int idx = blockIdx.x * 256 + threadIdx.x;
    int ec = idx & 7;
    int s  = (idx >> 3) & 2047;
    int bh = idx >> 14;
    int b = bh >> 3, h = bh & 7;
    const float* src = K + (((size_t)b * 2048 + s) * 8 + h) * 64 + ec * 8;
    float4 a = *(const float4*)src;
    float4 c = *(const float4*)(src + 4);
    uint4 val = { pk2(a.x, a.y), pk2(a.z, a.w), pk2(c.x, c.y), pk2(c.z, c.w) };
    *(uint4*)(Kh + (size_t)idx * 8) = val;
  } else {
    const int bid  = blockIdx.x - 2048;
    const int tid  = threadIdx.x;
    const int w    = tid >> 6;
    const int lane = tid & 63;
    const int u_   = lane >> 4;
    const int dq   = (lane >> 2) & 3;
    const int r_   = lane & 3;
    const unsigned selv = (lane & 1) ? 0x03020706u : 0x05040100u;

    int bh = bid >> 4;
    int s0 = (bid & 15) * 128;
    int b = bh >> 3, h = bh & 7;
    const float* Vb = V + ((size_t)b * 2048 * 8 + h) * 64;
    unsigned short* Vo = Vt + (size_t)bh * 64 * 2048;

    #pragma unroll
    for (int sp = 0; sp < 2; ++sp) {
      #pragma unroll
      for (int p = 0; p < 4; ++p) {
        int sl = w * 32 + sp * 16 + u_ * 4;
        int sg = s0 + sl + r_;
        int d0 = p * 16 + dq * 4;
        float4 f = *(const float4*)(Vb + (size_t)sg * 512 + d0);
        unsigned lo = pk2(f.x, f.y), hi = pk2(f.z, f.w);
        unsigned tlo = shflx(lo, 1), thi = shflx(hi, 1);
        lo = __builtin_amdgcn_perm(tlo, lo, selv);
        hi = __builtin_amdgcn_perm(thi, hi, selv);
        unsigned t2lo = shflx(lo, 2), t2hi = shflx(hi, 2);
        unsigned Aw = (lane & 2) ? t2hi : lo;
        unsigned Bw = (lane & 2) ? hi   : t2lo;
        int d = d0 + r_;
        uint2 wv = {Aw, Bw};
        *(uint2*)(Vo + (size_t)d * 2048 + s0 + sl) = wv;
      }
    }
  }
}

// ---------- main: 512 threads (8 waves), 16 q-rows ----------
extern "C" __global__ __launch_bounds__(512, 4)
void nma_kernel(const float* __restrict__ Q, const unsigned short* __restrict__ Kh,
                const unsigned short* __restrict__ Vt, const float* __restrict__ AW,
                float* __restrict__ Out)
{
  // LDS: [0,64K) sc[16 rows][2048] fp16, row q byte-swizzled ^((q&7)<<4)
  //      [64K,80K) work: hist1[16][256] (bins ROTATED: slot=(bin+4*row)&255)
  //                 -> h2[8 waves][512] -> PV partials (8KB)
  __shared__ __align__(16) char lds[81920];
  unsigned* work = (unsigned*)(lds + 65536);

  const int tid  = threadIdx.x;
  const int w    = tid >> 6;      // wave 0..7
  const int lane = tid & 63;
  const int g    = lane >> 4;
  const int lx   = lane & 15;

  // XCD-aware bijective swizzle (4096 % 8 == 0)
  int bid = blockIdx.x;
  int lb  = (bid & 7) * 512 + (bid >> 3);
  int bh  = lb >> 7;
  int b   = bh >> 3, hh = bh & 7;
  int l0  = (lb & 127) << 4;

  const float* Qb = Q + (((size_t)b * 2048 + l0) * 8 + hh) * 64;
  const unsigned short* Khb = Kh + (size_t)bh * 2048 * 64;
  const unsigned short* Vtb = Vt + (size_t)bh * 64 * 2048;

  // zero hist1 (4096 u32)
  {
    uint4 z4 = {0u,0u,0u,0u};
    uint4* p = (uint4*)work;
    p[tid] = z4;
    p[tid + 512] = z4;
  }

  // Q B-frag (col=lx, k=g*8..; two K-halves), scale QS folded (log2-domain scores)
  union FU { f16x8 v; unsigned u[4]; };
  FU qa0, qa1;
  {
    const float* qp = Qb + (size_t)lx * 512 + g * 8;
    float4 a = *(const float4*)(qp);
    float4 c = *(const float4*)(qp + 4);
    qa0.u[0] = pk2(a.x*QS, a.y*QS); qa0.u[1] = pk2(a.z*QS, a.w*QS);
    qa0.u[2] = pk2(c.x*QS, c.y*QS); qa0.u[3] = pk2(c.z*QS, c.w*QS);
    a = *(const float4*)(qp + 32);
    c = *(const float4*)(qp + 36);
    qa1.u[0] = pk2(a.x*QS, a.y*QS); qa1.u[1] = pk2(a.z*QS, a.w*QS);
    qa1.u[2] = pk2(c.x*QS, c.y*QS); qa1.u[3] = pk2(c.z*QS, c.w*QS);
  }
  __syncthreads();

  // ===== QK^T transposed: D[s][q] = mfma(A=K, B=Q); lane holds 4 consecutive s for q=lx =====
  const unsigned swl = ((unsigned)(lx & 7)) << 4;
  const unsigned rot = ((unsigned)lx) << 2;        // hist1 bin rotation for row lx
  unsigned* hq = work + lx * 256;
  #pragma unroll 4
  for (int t = 0; t < 16; ++t) {
    int s0 = (t * 8 + w) * 16;
    const unsigned short* kp = Khb + (size_t)(s0 + lx) * 64 + g * 8;
    f16x8 kb0 = *(const f16x8*)(kp);
    f16x8 kb1 = *(const f16x8*)(kp + 32);
    f32x4 acc = {0.f, 0.f, 0.f, 0.f};
    acc = __builtin_amdgcn_mfma_f32_16x16x32_f16(kb0, qa0.v, acc, 0, 0, 0);
    acc = __builtin_amdgcn_mfma_f32_16x16x32_f16(kb1, qa1.v, acc, 0, 0, 0);
    unsigned u0 = pk2(acc[0], acc[1]);
    unsigned u1 = pk2(acc[2], acc[3]);
    uint2 wv = {u0, u1};
    *(uint2*)(lds + lx * 4096 + (((unsigned)(s0 * 2 + g * 8)) ^ swl)) = wv;
    atomicAdd(&hq[((ou16_of(u0 & 0xFFFFu) >> 8) + rot) & 255u], 1u);
    atomicAdd(&hq[((ou16_of(u0 >> 16) >> 8) + rot) & 255u], 1u);
    atomicAdd(&hq[((ou16_of(u1 & 0xFFFFu) >> 8) + rot) & 255u], 1u);
    atomicAdd(&hq[((ou16_of(u1 >> 16) >> 8) + rot) & 255u], 1u);
  }
  __syncthreads();

  const float aw0 = AW[0], aw1 = AW[1], aw2 = AW[2];

  // ===== round 1: wave w owns rows 2w, 2w+1; one suffix scan per row =====
  unsigned d0a[2], d1a[2], d2a[2], k0a[2], k1a[2], k2a[2];
  #pragma unroll 2
  for (int rr = 0; rr < 2; ++rr) {
    int q = 2 * w + rr;
    // un-rotate: word (lane+q)&63 of row q's hist holds logical bins 4*lane..4*lane+3
    uint4 hb = ((const uint4*)(work + q * 256))[(lane + q) & 63];
    unsigned tail = suffix64(hb.x + hb.y + hb.z + hb.w, lane);
    unsigned p0 = pick_digit(tail, hb.x, hb.y, hb.z, hb.w, KSEL0, lane);
    unsigned p1 = pick_digit(tail, hb.x, hb.y, hb.z, hb.w, KSEL1, lane);
    unsigned p2 = pick_digit(tail, hb.x, hb.y, hb.z, hb.w, KSEL2, lane);
    d0a[rr] = p0 >> 16; k0a[rr] = p0 & 0xFFFFu;
    d1a[rr] = p1 >> 16; k1a[rr] = p1 & 0xFFFFu;
    d2a[rr] = p2 >> 16; k2a[rr] = p2 & 0xFFFFu;
  }

  // ===== round 2, fused: count+exp (1 LDS read) -> thresholds -> Z (regs) -> weights (1 LDS write) =====
  unsigned* hw2 = work + w * 512;
  #pragma unroll 1
  for (int rr = 0; rr < 2; ++rr) {
    int q = 2 * w + rr;
    const unsigned swq = ((unsigned)(q & 7)) << 4;
    char* rowp = lds + q * 4096;
    for (int i = lane; i < 512; i += 64) hw2[i] = 0u;
    unsigned D0 = d0a[rr], D1 = d1a[rr], D2 = d2a[rr];

    // P1: count restricted bins (packed D0|D1, D2 at +256) AND keep e=exp2(s-CSH2) in regs
    unsigned ereg[16];
    #pragma unroll
    for (int it = 0; it < 4; ++it) {
      uint4 dv = *(const uint4*)(rowp + (((unsigned)(it * 1024 + lane * 16)) ^ swq));
      unsigned ws[4] = {dv.x, dv.y, dv.z, dv.w};
      #pragma unroll
      for (int p = 0; p < 4; ++p) {
        unsigned b0 = ws[p] & 0xFFFFu, b1 = ws[p] >> 16;
        unsigned o0 = ou16_of(b0), o1 = ou16_of(b1);
        unsigned hi0 = o0 >> 8, lo0 = o0 & 255u;
        unsigned hi1 = o1 >> 8, lo1 = o1 & 255u;
        unsigned add0 = (hi0 == D0 ? 1u : 0u) | (hi0 == D1 ? 0x10000u : 0u);
        unsigned add1 = (hi1 == D0 ? 1u : 0u) | (hi1 == D1 ? 0x10000u : 0u);
        if (add0) atomicAdd(&hw2[lo0], add0);
        if (hi0 == D2) atomicAdd(&hw2[256 + lo0], 1u);
        if (add1) atomicAdd(&hw2[lo1], add1);
        if (hi1 == D2) atomicAdd(&hw2[256 + lo1], 1u);
        float e0 = exp2f(h2f(b0) - CSH2);
        float e1 = exp2f(h2f(b1) - CSH2);
        ereg[it * 4 + p] = pk2(e0, e1);
      }
    }
    // thresholds: packed scan covers D0 (lo16) and D1 (hi16) together; D2 separate
    uint4 pkv = ((const uint4*)hw2)[lane];
    uint4 d2v = ((const uint4*)(hw2 + 256))[lane];
    unsigned ptail = suffix64(pkv.x + pkv.y + pkv.z + pkv.w, lane);
    unsigned hx = pkv.x & 0xFFFFu, hy = pkv.y & 0xFFFFu, hz = pkv.z & 0xFFFFu, hw_ = pkv.w & 0xFFFFu;
    unsigned T1o = (D0 << 8) | (pick_digit(ptail & 0xFFFFu, hx, hy, hz, hw_, k0a[rr], lane) >> 16);
    hx = pkv.x >> 16; hy = pkv.y >> 16; hz = pkv.z >> 16; hw_ = pkv.w >> 16;
    unsigned T2o = (D1 << 8) | (pick_digit(ptail >> 16, hx, hy, hz, hw_, k1a[rr], lane) >> 16);
    unsigned t2 = suffix64(d2v.x + d2v.y + d2v.z + d2v.w, lane);
    unsigned T3o = (D2 << 8) | (pick_digit(t2, d2v.x, d2v.y, d2v.z, d2v.w, k2a[rr], lane) >> 16);
    // e-bit thresholds (e>0, monotone in bits)
    unsigned e1b = pk2(exp2f(h2f(ou16_inv(T1o)) - CSH2), 0.f) & 0xFFFFu;
    unsigned e2b = pk2(exp2f(h2f(ou16_inv(T2o)) - CSH2), 0.f) & 0xFFFFu;
    unsigned e3b = pk2(exp2f(h2f(ou16_inv(T3o)) - CSH2), 0.f) & 0xFFFFu;

    // P2: Z from regs, band-bucketed (nested z1 ⊇ z2 ⊇ z3)
    float zbA = 0.f, zbB = 0.f, zbC = 0.f;
    #pragma unroll
    for (int i = 0; i < 16; ++i) {
      unsigned uu = ereg[i];
      unsigned b0 = uu & 0xFFFFu, b1 = uu >> 16;
      float e0 = h2f(b0), e1 = h2f(b1);
      if (b0 >= e1b) zbA += e0; else if (b0 >= e2b) zbB += e0; else if (b0 >= e3b) zbC += e0;
      if (b1 >= e1b) zbA += e1; else if (b1 >= e2b) zbB += e1; else if (b1 >= e3b) zbC += e1;
    }
    #pragma unroll
    for (int off = 1; off < 64; off <<= 1) {
      zbA += __shfl_xor(zbA, off, 64);
      zbB += __shfl_xor(zbB, off, 64);
      zbC += __shfl_xor(zbC, off, 64);
    }
    float z1 = zbA, z2 = zbA + zbB, z3 = z2 + zbC;
    float A3 = aw2 / z3;
    float A2 = aw1 / z2 + A3;
    float A1 = aw0 / z1 + A2;
    unsigned A1b = pk2(A1 * WSC, 0.f) & 0xFFFFu;
    unsigned A2b = pk2(A2 * WSC, 0.f) & 0xFFFFu;
    unsigned A3b = pk2(A3 * WSC, 0.f) & 0xFFFFu;

    // P3: weights from regs, packed fp16 multiply, single LDS write
    #pragma unroll
    for (int it = 0; it < 4; ++it) {
      unsigned no[4];
      #pragma unroll
      for (int p = 0; p < 4; ++p) {
        unsigned uu = ereg[it * 4 + p];
        unsigned b0 = uu & 0xFFFFu, b1 = uu >> 16;
        unsigned c0 = (b0 >= e1b) ? A1b : (b0 >= e2b) ? A2b : (b0 >= e3b) ? A3b : 0u;
        unsigned c1 = (b1 >= e1b) ? A1b : (b1 >= e2b) ? A2b : (b1 >= e3b) ? A3b : 0u;
        unsigned cw = c0 | (c1 << 16);
        __half2 prod = *(__half2*)&uu * *(__half2*)&cw;   // v_pk_mul_f16
        no[p] = *(unsigned*)&prod;
      }
      uint4 nv = {no[0], no[1], no[2], no[3]};
      *(uint4*)(rowp + (((unsigned)(it * 1024 + lane * 16)) ^ swq)) = nv;
    }
  }

  // ===== PV prefetch: issue first 4 Vt loads before the barrier =====
  const int dt = (w >> 1) * 16;
  const int sh = w & 1;
  const unsigned short* vp = Vtb + (size_t)(dt + lx) * 2048 + sh * 1024 + g * 8;
  f16x8 pv0 = *(const f16x8*)(vp);
  f16x8 pv1 = *(const f16x8*)(vp + 32);
  f16x8 pv2 = *(const f16x8*)(vp + 64);
  f16x8 pv3 = *(const f16x8*)(vp + 96);
  __syncthreads();

  // ===== PV: out^T[d][q] = sum_s Vt[d][s] * w[q][s]; 8 waves = 4 d-tiles x 2 s-halves =====
  f32x4 oacc = {0.f, 0.f, 0.f, 0.f};
  const char* bp = lds + lx * 4096;
  const unsigned sbase = (unsigned)((sh * 1024 + g * 8) * 2);

  oacc = __builtin_amdgcn_mfma_f32_16x16x32_f16(pv0,
           *(const f16x8*)(bp + ((sbase +   0u) ^ swl)), oacc, 0, 0, 0);
  oacc = __builtin_amdgcn_mfma_f32_16x16x32_f16(pv1,
           *(const f16x8*)(bp + ((sbase +  64u) ^ swl)), oacc, 0, 0, 0);
  oacc = __builtin_amdgcn_mfma_f32_16x16x32_f16(pv2,
           *(const f16x8*)(bp + ((sbase + 128u) ^ swl)), oacc, 0, 0, 0);
  oacc = __builtin_amdgcn_mfma_f32_16x16x32_f16(pv3,
           *(const f16x8*)(bp + ((sbase + 192u) ^ swl)), oacc, 0, 0, 0);

  #pragma unroll 4
  for (int kc = 4; kc < 32; ++kc) {
    f16x8 av = *(const f16x8*)(vp + kc * 32);
    f16x8 bv = *(const f16x8*)(bp + ((sbase + (unsigned)(kc * 64)) ^ swl));
    oacc = __builtin_amdgcn_mfma_f32_16x16x32_f16(av, bv, oacc, 0, 0, 0);
  }

  float* pbuf = (float*)work;   // 8 waves x 256 floats = 8KB
  *(f32x4*)(pbuf + w * 256 + lx * 16 + g * 4) = oacc;
  __syncthreads();
  if (w < 4) {
    const float* pa = pbuf + (2 * w) * 256 + lx * 16 + g * 4;
    float4 ra = *(const float4*)pa;
    float4 rb = *(const float4*)(pa + 256);
    float* op = Out + (((size_t)b * 2048 + l0 + lx) * 8 + hh) * 64 + w * 16 + g * 4;
    float4 ov = { (ra.x + rb.x) * (1.f/WSC), (ra.y + rb.y) * (1.f/WSC),
                  (ra.z + rb.z) * (1.f/WSC), (ra.w + rb.w) * (1.f/WSC) };
    *(float4*)op = ov;
  }
}

extern "C" void kernel_launch(void* const* d_in, const int* in_sizes, int n_in,
                              void* d_out, int out_size, void* d_ws, size_t ws_size,
                              hipStream_t stream) {
  (void)in_sizes; (void)n_in; (void)out_size; (void)ws_size;
  const float* Q  = (const float*)d_in[0];
  const float* K  = (const float*)d_in[1];
  const float* V  = (const float*)d_in[2];
  const float* AW = (const float*)d_in[3];
  unsigned short* Kh = (unsigned short*)d_ws;                    // 8.4 MB
  unsigned short* Vt = (unsigned short*)((char*)d_ws + 8388608); // 8.4 MB
  prep_kv<<<dim3(2560), dim3(256), 0, stream>>>(K, V, Kh, Vt);
  nma_kernel<<<dim3(4096), dim3(512), 0, stream>>>(Q, Kh, Vt, AW, (float*)d_out);
}

// Round 13
// 350.373 us; speedup vs baseline: 1.0159x; 1.0159x over previous
//
#include <hip/hip_runtime.h>
#include <hip/hip_fp16.h>

typedef _Float16 f16x8 __attribute__((ext_vector_type(8)));
typedef float f32x4 __attribute__((ext_vector_type(4)));

#define KSEL0 1372u   // int(2048*0.67)
#define KSEL1 1536u   // int(2048*0.75)
#define KSEL2 1638u   // int(2048*0.80)
#define WSC 16.0f
#define QS   0.1803368801f   // 0.125 * log2(e): scores stored in log2-domain
#define CSH2 11.5416222f     // 8 * log2(e): e = exp2(s' - CSH2) == exp(s - 8)

__device__ __forceinline__ unsigned ou16_inv(unsigned ou) {
  return (ou & 0x8000u) ? (ou ^ 0x8000u) : (ou ^ 0xFFFFu);
}
// packed monotone key for TWO fp16 values in one u32 (4 ops)
__device__ __forceinline__ unsigned ou16x2(unsigned uu) {
  return uu ^ 0x80008000u ^ (((uu >> 15) & 0x00010001u) * 0x7FFFu);
}
__device__ __forceinline__ unsigned pk2(float a, float b) {
  auto h = __builtin_amdgcn_cvt_pkrtz(a, b);
  return __builtin_bit_cast(unsigned, h);
}
__device__ __forceinline__ unsigned shflx(unsigned v, int m) {
  return (unsigned)__shfl_xor((int)v, m, 64);
}
__device__ __forceinline__ float h2f(unsigned bits16) {
  return __half2float(__ushort_as_half((unsigned short)bits16));
}

// inclusive suffix-sum over 64 lanes (u32 add; packed 16-bit fields safe when
// each field's total < 65536 — counts here are <= 2048)
__device__ __forceinline__ unsigned suffix64(unsigned s4, int lane) {
  unsigned p = s4;
  #pragma unroll
  for (int off = 1; off < 64; off <<= 1) {
    int sl = lane + off;
    unsigned t = (unsigned)__shfl((int)p, sl < 64 ? sl : lane, 64);
    p += (sl < 64) ? t : 0u;
  }
  return p;
}
// per-lane bin counts (logical bins 4l..4l+3) + suffix tail -> k-th-largest digit
// returns (digit<<16) | remainder-k
__device__ __forceinline__ unsigned pick_digit(unsigned tail, unsigned hx, unsigned hy,
                                               unsigned hz, unsigned hw_, unsigned k, int lane) {
  unsigned s4 = hx + hy + hz + hw_;
  unsigned a3 = tail - s4;
  unsigned a2 = a3 + hw_;
  unsigned a1 = a2 + hz;
  unsigned a0 = a1 + hy;
  int d = -1; unsigned nk = 0;
  if (a3 < k && a3 + hw_ >= k)      { d = 4*lane+3; nk = k - a3; }
  else if (a2 < k && a2 + hz >= k)  { d = 4*lane+2; nk = k - a2; }
  else if (a1 < k && a1 + hy >= k)  { d = 4*lane+1; nk = k - a1; }
  else if (a0 < k && a0 + hx >= k)  { d = 4*lane+0; nk = k - a0; }
  unsigned long long mb = __ballot(d >= 0);
  int src = __ffsll(mb) - 1;
  unsigned pack = ((unsigned)d << 16) | nk;
  return (unsigned)__shfl((int)pack, src, 64);
}

// ---------- fused prep: K fp32 -> Kh fp16 [bh][s][e]; V fp32 -> Vt fp16 [bh][d][s] ----------
extern "C" __global__ __launch_bounds__(256)
void prep_kv(const float* __restrict__ K, const float* __restrict__ V,
             unsigned short* __restrict__ Kh, unsigned short* __restrict__ Vt) {
  if (blockIdx.x < 2048) {
    int idx = blockIdx.x * 256 + threadIdx.x;
    int ec = idx & 7;
    int s  = (idx >> 3) & 2047;
    int bh = idx >> 14;
    int b = bh >> 3, h = bh & 7;
    const float* src = K + (((size_t)b * 2048 + s) * 8 + h) * 64 + ec * 8;
    float4 a = *(const float4*)src;
    float4 c = *(const float4*)(src + 4);
    uint4 val = { pk2(a.x, a.y), pk2(a.z, a.w), pk2(c.x, c.y), pk2(c.z, c.w) };
    *(uint4*)(Kh + (size_t)idx * 8) = val;
  } else {
    const int bid  = blockIdx.x - 2048;
    const int tid  = threadIdx.x;
    const int w    = tid >> 6;
    const int lane = tid & 63;
    const int u_   = lane >> 4;
    const int dq   = (lane >> 2) & 3;
    const int r_   = lane & 3;
    const unsigned selv = (lane & 1) ? 0x03020706u : 0x05040100u;

    int bh = bid >> 4;
    int s0 = (bid & 15) * 128;
    int b = bh >> 3, h = bh & 7;
    const float* Vb = V + ((size_t)b * 2048 * 8 + h) * 64;
    unsigned short* Vo = Vt + (size_t)bh * 64 * 2048;

    #pragma unroll
    for (int sp = 0; sp < 2; ++sp) {
      #pragma unroll
      for (int p = 0; p < 4; ++p) {
        int sl = w * 32 + sp * 16 + u_ * 4;
        int sg = s0 + sl + r_;
        int d0 = p * 16 + dq * 4;
        float4 f = *(const float4*)(Vb + (size_t)sg * 512 + d0);
        unsigned lo = pk2(f.x, f.y), hi = pk2(f.z, f.w);
        unsigned tlo = shflx(lo, 1), thi = shflx(hi, 1);
        lo = __builtin_amdgcn_perm(tlo, lo, selv);
        hi = __builtin_amdgcn_perm(thi, hi, selv);
        unsigned t2lo = shflx(lo, 2), t2hi = shflx(hi, 2);
        unsigned Aw = (lane & 2) ? t2hi : lo;
        unsigned Bw = (lane & 2) ? hi   : t2lo;
        int d = d0 + r_;
        uint2 wv = {Aw, Bw};
        *(uint2*)(Vo + (size_t)d * 2048 + s0 + sl) = wv;
      }
    }
  }
}

// ---------- main: 512 threads (8 waves), 16 q-rows ----------
extern "C" __global__ __launch_bounds__(512, 4)
void nma_kernel(const float* __restrict__ Q, const unsigned short* __restrict__ Kh,
                const unsigned short* __restrict__ Vt, const float* __restrict__ AW,
                float* __restrict__ Out)
{
  // LDS: [0,64K) sc[16 rows][2048] fp16, row q byte-swizzled ^((q&7)<<4)
  //      [64K,80K) work: hist1[16][256] (bins ROTATED slot=(bin+4*row)&255,
  //                 counts g-SPLIT: g<2 in lo16, g>=2 in hi16)
  //                 -> h2[8 waves][512] -> PV partials (8KB)
  __shared__ __align__(16) char lds[81920];
  unsigned* work = (unsigned*)(lds + 65536);

  const int tid  = threadIdx.x;
  const int w    = tid >> 6;      // wave 0..7
  const int lane = tid & 63;
  const int g    = lane >> 4;
  const int lx   = lane & 15;

  // XCD-aware bijective swizzle (4096 % 8 == 0)
  int bid = blockIdx.x;
  int lb  = (bid & 7) * 512 + (bid >> 3);
  int bh  = lb >> 7;
  int b   = bh >> 3, hh = bh & 7;
  int l0  = (lb & 127) << 4;

  const float* Qb = Q + (((size_t)b * 2048 + l0) * 8 + hh) * 64;
  const unsigned short* Khb = Kh + (size_t)bh * 2048 * 64;
  const unsigned short* Vtb = Vt + (size_t)bh * 64 * 2048;

  // zero hist1 (4096 u32)
  {
    uint4 z4 = {0u,0u,0u,0u};
    uint4* p = (uint4*)work;
    p[tid] = z4;
    p[tid + 512] = z4;
  }

  // Q B-frag (col=lx, k=g*8..; two K-halves), scale QS folded (log2-domain scores)
  union FU { f16x8 v; unsigned u[4]; };
  FU qa0, qa1;
  {
    const float* qp = Qb + (size_t)lx * 512 + g * 8;
    float4 a = *(const float4*)(qp);
    float4 c = *(const float4*)(qp + 4);
    qa0.u[0] = pk2(a.x*QS, a.y*QS); qa0.u[1] = pk2(a.z*QS, a.w*QS);
    qa0.u[2] = pk2(c.x*QS, c.y*QS); qa0.u[3] = pk2(c.z*QS, c.w*QS);
    a = *(const float4*)(qp + 32);
    c = *(const float4*)(qp + 36);
    qa1.u[0] = pk2(a.x*QS, a.y*QS); qa1.u[1] = pk2(a.z*QS, a.w*QS);
    qa1.u[2] = pk2(c.x*QS, c.y*QS); qa1.u[3] = pk2(c.z*QS, c.w*QS);
  }
  __syncthreads();

  // ===== QK^T transposed: D[s][q] = mfma(A=K, B=Q); lane holds 4 consecutive s for q=lx =====
  const unsigned swl = ((unsigned)(lx & 7)) << 4;
  const unsigned rot = ((unsigned)lx) << 2;        // hist1 bin rotation for row lx
  const unsigned hinc = (g < 2) ? 1u : 0x10000u;   // g-split counter field
  unsigned* hq = work + lx * 256;
  #pragma unroll 4
  for (int t = 0; t < 16; ++t) {
    int s0 = (t * 8 + w) * 16;
    const unsigned short* kp = Khb + (size_t)(s0 + lx) * 64 + g * 8;
    f16x8 kb0 = *(const f16x8*)(kp);
    f16x8 kb1 = *(const f16x8*)(kp + 32);
    f32x4 acc = {0.f, 0.f, 0.f, 0.f};
    acc = __builtin_amdgcn_mfma_f32_16x16x32_f16(kb0, qa0.v, acc, 0, 0, 0);
    acc = __builtin_amdgcn_mfma_f32_16x16x32_f16(kb1, qa1.v, acc, 0, 0, 0);
    unsigned u0 = pk2(acc[0], acc[1]);
    unsigned u1 = pk2(acc[2], acc[3]);
    uint2 wv = {u0, u1};
    *(uint2*)(lds + lx * 4096 + (((unsigned)(s0 * 2 + g * 8)) ^ swl)) = wv;
    unsigned o20 = ou16x2(u0), o21 = ou16x2(u1);
    atomicAdd(&hq[(((o20 >>  8) & 255u) + rot) & 255u], hinc);
    atomicAdd(&hq[(( o20 >> 24)         + rot) & 255u], hinc);
    atomicAdd(&hq[(((o21 >>  8) & 255u) + rot) & 255u], hinc);
    atomicAdd(&hq[(( o21 >> 24)         + rot) & 255u], hinc);
  }
  __syncthreads();

  const float aw0 = AW[0], aw1 = AW[1], aw2 = AW[2];

  // ===== round 1: wave w owns rows 2w, 2w+1; one suffix scan per row =====
  unsigned d0a[2], d1a[2], d2a[2], k0a[2], k1a[2], k2a[2];
  #pragma unroll 2
  for (int rr = 0; rr < 2; ++rr) {
    int q = 2 * w + rr;
    // un-rotate: word (lane+q)&63 of row q's hist holds logical bins 4*lane..4*lane+3
    uint4 hr = ((const uint4*)(work + q * 256))[(lane + q) & 63];
    unsigned hbx = (hr.x & 0xFFFFu) + (hr.x >> 16);
    unsigned hby = (hr.y & 0xFFFFu) + (hr.y >> 16);
    unsigned hbz = (hr.z & 0xFFFFu) + (hr.z >> 16);
    unsigned hbw = (hr.w & 0xFFFFu) + (hr.w >> 16);
    unsigned tail = suffix64(hbx + hby + hbz + hbw, lane);
    unsigned p0 = pick_digit(tail, hbx, hby, hbz, hbw, KSEL0, lane);
    unsigned p1 = pick_digit(tail, hbx, hby, hbz, hbw, KSEL1, lane);
    unsigned p2 = pick_digit(tail, hbx, hby, hbz, hbw, KSEL2, lane);
    d0a[rr] = p0 >> 16; k0a[rr] = p0 & 0xFFFFu;
    d1a[rr] = p1 >> 16; k1a[rr] = p1 & 0xFFFFu;
    d2a[rr] = p2 >> 16; k2a[rr] = p2 & 0xFFFFu;
  }

  // ===== round 2, fused: count+exp (1 LDS read) -> thresholds -> Z (regs) -> weights (1 LDS write) =====
  unsigned* hw2 = work + w * 512;
  #pragma unroll 1
  for (int rr = 0; rr < 2; ++rr) {
    int q = 2 * w + rr;
    const unsigned swq = ((unsigned)(q & 7)) << 4;
    char* rowp = lds + q * 4096;
    for (int i = lane; i < 512; i += 64) hw2[i] = 0u;
    unsigned D0 = d0a[rr], D1 = d1a[rr], D2 = d2a[rr];

    // P1: count restricted bins (packed D0|D1, D2 at +256) AND keep e=exp2(s-CSH2) in regs
    unsigned ereg[16];
    #pragma unroll
    for (int it = 0; it < 4; ++it) {
      uint4 dv = *(const uint4*)(rowp + (((unsigned)(it * 1024 + lane * 16)) ^ swq));
      unsigned ws[4] = {dv.x, dv.y, dv.z, dv.w};
      #pragma unroll
      for (int p = 0; p < 4; ++p) {
        unsigned uu = ws[p];
        unsigned b0 = uu & 0xFFFFu, b1 = uu >> 16;
        unsigned o2 = ou16x2(uu);
        unsigned hi0 = (o2 >> 8) & 255u, lo0 = o2 & 255u;
        unsigned hi1 = o2 >> 24,         lo1 = (o2 >> 16) & 255u;
        unsigned add0 = (hi0 == D0 ? 1u : 0u) | (hi0 == D1 ? 0x10000u : 0u);
        unsigned add1 = (hi1 == D0 ? 1u : 0u) | (hi1 == D1 ? 0x10000u : 0u);
        if (add0) atomicAdd(&hw2[lo0], add0);
        if (hi0 == D2) atomicAdd(&hw2[256 + lo0], 1u);
        if (add1) atomicAdd(&hw2[lo1], add1);
        if (hi1 == D2) atomicAdd(&hw2[256 + lo1], 1u);
        float e0 = exp2f(h2f(b0) - CSH2);
        float e1 = exp2f(h2f(b1) - CSH2);
        ereg[it * 4 + p] = pk2(e0, e1);
      }
    }
    // thresholds: packed scan covers D0 (lo16) and D1 (hi16) together; D2 separate
    uint4 pkv = ((const uint4*)hw2)[lane];
    uint4 d2v = ((const uint4*)(hw2 + 256))[lane];
    unsigned ptail = suffix64(pkv.x + pkv.y + pkv.z + pkv.w, lane);
    unsigned hx = pkv.x & 0xFFFFu, hy = pkv.y & 0xFFFFu, hz = pkv.z & 0xFFFFu, hw_ = pkv.w & 0xFFFFu;
    unsigned T1o = (D0 << 8) | (pick_digit(ptail & 0xFFFFu, hx, hy, hz, hw_, k0a[rr], lane) >> 16);
    hx = pkv.x >> 16; hy = pkv.y >> 16; hz = pkv.z >> 16; hw_ = pkv.w >> 16;
    unsigned T2o = (D1 << 8) | (pick_digit(ptail >> 16, hx, hy, hz, hw_, k1a[rr], lane) >> 16);
    unsigned t2 = suffix64(d2v.x + d2v.y + d2v.z + d2v.w, lane);
    unsigned T3o = (D2 << 8) | (pick_digit(t2, d2v.x, d2v.y, d2v.z, d2v.w, k2a[rr], lane) >> 16);
    // e-bit thresholds (e>0, monotone in bits)
    unsigned e1b = pk2(exp2f(h2f(ou16_inv(T1o)) - CSH2), 0.f) & 0xFFFFu;
    unsigned e2b = pk2(exp2f(h2f(ou16_inv(T2o)) - CSH2), 0.f) & 0xFFFFu;
    unsigned e3b = pk2(exp2f(h2f(ou16_inv(T3o)) - CSH2), 0.f) & 0xFFFFu;

    // P2: Z from regs, band-bucketed (nested z1 ⊇ z2 ⊇ z3)
    float zbA = 0.f, zbB = 0.f, zbC = 0.f;
    #pragma unroll
    for (int i = 0; i < 16; ++i) {
      unsigned uu = ereg[i];
      unsigned b0 = uu & 0xFFFFu, b1 = uu >> 16;
      float e0 = h2f(b0), e1 = h2f(b1);
      if (b0 >= e1b) zbA += e0; else if (b0 >= e2b) zbB += e0; else if (b0 >= e3b) zbC += e0;
      if (b1 >= e1b) zbA += e1; else if (b1 >= e2b) zbB += e1; else if (b1 >= e3b) zbC += e1;
    }
    #pragma unroll
    for (int off = 1; off < 64; off <<= 1) {
      zbA += __shfl_xor(zbA, off, 64);
      zbB += __shfl_xor(zbB, off, 64);
      zbC += __shfl_xor(zbC, off, 64);
    }
    float z1 = zbA, z2 = zbA + zbB, z3 = z2 + zbC;
    float A3 = aw2 / z3;
    float A2 = aw1 / z2 + A3;
    float A1 = aw0 / z1 + A2;
    unsigned A1b = pk2(A1 * WSC, 0.f) & 0xFFFFu;
    unsigned A2b = pk2(A2 * WSC, 0.f) & 0xFFFFu;
    unsigned A3b = pk2(A3 * WSC, 0.f) & 0xFFFFu;

    // P3: weights from regs, packed fp16 multiply, single LDS write
    #pragma unroll
    for (int it = 0; it < 4; ++it) {
      unsigned no[4];
      #pragma unroll
      for (int p = 0; p < 4; ++p) {
        unsigned uu = ereg[it * 4 + p];
        unsigned b0 = uu & 0xFFFFu, b1 = uu >> 16;
        unsigned c0 = (b0 >= e1b) ? A1b : (b0 >= e2b) ? A2b : (b0 >= e3b) ? A3b : 0u;
        unsigned c1 = (b1 >= e1b) ? A1b : (b1 >= e2b) ? A2b : (b1 >= e3b) ? A3b : 0u;
        unsigned cw = c0 | (c1 << 16);
        __half2 prod = *(__half2*)&uu * *(__half2*)&cw;   // v_pk_mul_f16
        no[p] = *(unsigned*)&prod;
      }
      uint4 nv = {no[0], no[1], no[2], no[3]};
      *(uint4*)(rowp + (((unsigned)(it * 1024 + lane * 16)) ^ swq)) = nv;
    }
  }

  // ===== PV prefetch: issue first 4 Vt loads before the barrier =====
  const int dt = (w >> 1) * 16;
  const int sh = w & 1;
  const unsigned short* vp = Vtb + (size_t)(dt + lx) * 2048 + sh * 1024 + g * 8;
  f16x8 pv0 = *(const f16x8*)(vp);
  f16x8 pv1 = *(const f16x8*)(vp + 32);
  f16x8 pv2 = *(const f16x8*)(vp + 64);
  f16x8 pv3 = *(const f16x8*)(vp + 96);
  __syncthreads();

  // ===== PV: out^T[d][q] = sum_s Vt[d][s] * w[q][s]; 8 waves = 4 d-tiles x 2 s-halves =====
  f32x4 oacc = {0.f, 0.f, 0.f, 0.f};
  const char* bp = lds + lx * 4096;
  const unsigned sbase = (unsigned)((sh * 1024 + g * 8) * 2);

  oacc = __builtin_amdgcn_mfma_f32_16x16x32_f16(pv0,
           *(const f16x8*)(bp + ((sbase +   0u) ^ swl)), oacc, 0, 0, 0);
  oacc = __builtin_amdgcn_mfma_f32_16x16x32_f16(pv1,
           *(const f16x8*)(bp + ((sbase +  64u) ^ swl)), oacc, 0, 0, 0);
  oacc = __builtin_amdgcn_mfma_f32_16x16x32_f16(pv2,
           *(const f16x8*)(bp + ((sbase + 128u) ^ swl)), oacc, 0, 0, 0);
  oacc = __builtin_amdgcn_mfma_f32_16x16x32_f16(pv3,
           *(const f16x8*)(bp + ((sbase + 192u) ^ swl)), oacc, 0, 0, 0);

  #pragma unroll 4
  for (int kc = 4; kc < 32; ++kc) {
    f16x8 av = *(const f16x8*)(vp + kc * 32);
    f16x8 bv = *(const f16x8*)(bp + ((sbase + (unsigned)(kc * 64)) ^ swl));
    oacc = __builtin_amdgcn_mfma_f32_16x16x32_f16(av, bv, oacc, 0, 0, 0);
  }

  float* pbuf = (float*)work;   // 8 waves x 256 floats = 8KB
  *(f32x4*)(pbuf + w * 256 + lx * 16 + g * 4) = oacc;
  __syncthreads();
  if (w < 4) {
    const float* pa = pbuf + (2 * w) * 256 + lx * 16 + g * 4;
    float4 ra = *(const float4*)pa;
    float4 rb = *(const float4*)(pa + 256);
    float* op = Out + (((size_t)b * 2048 + l0 + lx) * 8 + hh) * 64 + w * 16 + g * 4;
    float4 ov = { (ra.x + rb.x) * (1.f/WSC), (ra.y + rb.y) * (1.f/WSC),
                  (ra.z + rb.z) * (1.f/WSC), (ra.w + rb.w) * (1.f/WSC) };
    *(float4*)op = ov;
  }
}

extern "C" void kernel_launch(void* const* d_in, const int* in_sizes, int n_in,
                              void* d_out, int out_size, void* d_ws, size_t ws_size,
                              hipStream_t stream) {
  (void)in_sizes; (void)n_in; (void)out_size; (void)ws_size;
  const float* Q  = (const float*)d_in[0];
  const float* K  = (const float*)d_in[1];
  const float* V  = (const float*)d_in[2];
  const float* AW = (const float*)d_in[3];
  unsigned short* Kh = (unsigned short*)d_ws;                    // 8.4 MB
  unsigned short* Vt = (unsigned short*)((char*)d_ws + 8388608); // 8.4 MB
  prep_kv<<<dim3(2560), dim3(256), 0, stream>>>(K, V, Kh, Vt);
  nma_kernel<<<dim3(4096), dim3(512), 0, stream>>>(Q, Kh, Vt, AW, (float*)d_out);
}

// Round 14
// 350.294 us; speedup vs baseline: 1.0161x; 1.0002x over previous
//
#include <hip/hip_runtime.h>
#include <hip/hip_fp16.h>

typedef _Float16 f16x8 __attribute__((ext_vector_type(8)));
typedef float f32x4 __attribute__((ext_vector_type(4)));

#define KSEL0 1372u   // int(2048*0.67)
#define KSEL1 1536u   // int(2048*0.75)
#define KSEL2 1638u   // int(2048*0.80)
#define WSC 16.0f
#define QS   0.1803368801f   // 0.125 * log2(e): scores stored in log2-domain
#define CSH2 11.5416222f     // 8 * log2(e): e = exp2(s' - CSH2) == exp(s - 8)

__device__ __forceinline__ unsigned ou16_inv(unsigned ou) {
  return (ou & 0x8000u) ? (ou ^ 0x8000u) : (ou ^ 0xFFFFu);
}
// packed monotone key for TWO fp16 values in one u32 (4 ops)
__device__ __forceinline__ unsigned ou16x2(unsigned uu) {
  return uu ^ 0x80008000u ^ (((uu >> 15) & 0x00010001u) * 0x7FFFu);
}
__device__ __forceinline__ unsigned pk2(float a, float b) {
  auto h = __builtin_amdgcn_cvt_pkrtz(a, b);
  return __builtin_bit_cast(unsigned, h);
}
__device__ __forceinline__ unsigned shflx(unsigned v, int m) {
  return (unsigned)__shfl_xor((int)v, m, 64);
}
__device__ __forceinline__ float h2f(unsigned bits16) {
  return __half2float(__ushort_as_half((unsigned short)bits16));
}

// inclusive suffix-sum over 64 lanes (u32 add; packed 16-bit fields safe when
// each field's total < 65536 — counts here are <= 2048)
__device__ __forceinline__ unsigned suffix64(unsigned s4, int lane) {
  unsigned p = s4;
  #pragma unroll
  for (int off = 1; off < 64; off <<= 1) {
    int sl = lane + off;
    unsigned t = (unsigned)__shfl((int)p, sl < 64 ? sl : lane, 64);
    p += (sl < 64) ? t : 0u;
  }
  return p;
}
// per-lane bin counts (logical bins 4l..4l+3) + suffix tail -> k-th-largest digit
// returns (digit<<16) | remainder-k
__device__ __forceinline__ unsigned pick_digit(unsigned tail, unsigned hx, unsigned hy,
                                               unsigned hz, unsigned hw_, unsigned k, int lane) {
  unsigned s4 = hx + hy + hz + hw_;
  unsigned a3 = tail - s4;
  unsigned a2 = a3 + hw_;
  unsigned a1 = a2 + hz;
  unsigned a0 = a1 + hy;
  int d = -1; unsigned nk = 0;
  if (a3 < k && a3 + hw_ >= k)      { d = 4*lane+3; nk = k - a3; }
  else if (a2 < k && a2 + hz >= k)  { d = 4*lane+2; nk = k - a2; }
  else if (a1 < k && a1 + hy >= k)  { d = 4*lane+1; nk = k - a1; }
  else if (a0 < k && a0 + hx >= k)  { d = 4*lane+0; nk = k - a0; }
  unsigned long long mb = __ballot(d >= 0);
  int src = __ffsll(mb) - 1;
  unsigned pack = ((unsigned)d << 16) | nk;
  return (unsigned)__shfl((int)pack, src, 64);
}

// ---------- fused prep: K fp32 -> Kh fp16 [bh][s][e]; V fp32 -> Vt fp16 [bh][d][s] ----------
extern "C" __global__ __launch_bounds__(256)
void prep_kv(const float* __restrict__ K, const float* __restrict__ V,
             unsigned short* __restrict__ Kh, unsigned short* __restrict__ Vt) {
  if (blockIdx.x < 2048) {
    int idx = blockIdx.x * 256 + threadIdx.x;
    int ec = idx & 7;
    int s  = (idx >> 3) & 2047;
    int bh = idx >> 14;
    int b = bh >> 3, h = bh & 7;
    const float* src = K + (((size_t)b * 2048 + s) * 8 + h) * 64 + ec * 8;
    float4 a = *(const float4*)src;
    float4 c = *(const float4*)(src + 4);
    uint4 val = { pk2(a.x, a.y), pk2(a.z, a.w), pk2(c.x, c.y), pk2(c.z, c.w) };
    *(uint4*)(Kh + (size_t)idx * 8) = val;
  } else {
    const int bid  = blockIdx.x - 2048;
    const int tid  = threadIdx.x;
    const int w    = tid >> 6;
    const int lane = tid & 63;
    const int u_   = lane >> 4;
    const int dq   = (lane >> 2) & 3;
    const int r_   = lane & 3;
    const unsigned selv = (lane & 1) ? 0x03020706u : 0x05040100u;

    int bh = bid >> 4;
    int s0 = (bid & 15) * 128;
    int b = bh >> 3, h = bh & 7;
    const float* Vb = V + ((size_t)b * 2048 * 8 + h) * 64;
    unsigned short* Vo = Vt + (size_t)bh * 64 * 2048;

    #pragma unroll
    for (int sp = 0; sp < 2; ++sp) {
      #pragma unroll
      for (int p = 0; p < 4; ++p) {
        int sl = w * 32 + sp * 16 + u_ * 4;
        int sg = s0 + sl + r_;
        int d0 = p * 16 + dq * 4;
        float4 f = *(const float4*)(Vb + (size_t)sg * 512 + d0);
        unsigned lo = pk2(f.x, f.y), hi = pk2(f.z, f.w);
        unsigned tlo = shflx(lo, 1), thi = shflx(hi, 1);
        lo = __builtin_amdgcn_perm(tlo, lo, selv);
        hi = __builtin_amdgcn_perm(thi, hi, selv);
        unsigned t2lo = shflx(lo, 2), t2hi = shflx(hi, 2);
        unsigned Aw = (lane & 2) ? t2hi : lo;
        unsigned Bw = (lane & 2) ? hi   : t2lo;
        int d = d0 + r_;
        uint2 wv = {Aw, Bw};
        *(uint2*)(Vo + (size_t)d * 2048 + s0 + sl) = wv;
      }
    }
  }
}

// ---------- main: 512 threads (8 waves), 16 q-rows ----------
extern "C" __global__ __launch_bounds__(512, 4)
void nma_kernel(const float* __restrict__ Q, const unsigned short* __restrict__ Kh,
                const unsigned short* __restrict__ Vt, const float* __restrict__ AW,
                float* __restrict__ Out)
{
  // LDS: [0,64K) sc[16 rows][2048] fp16, row q byte-swizzled ^((q&7)<<4)
  //      [64K,80K) work: hist1[16][256] (bins ROTATED slot=(bin+4*row)&255,
  //                 counts g-SPLIT: g<2 in lo16, g>=2 in hi16)
  //                 -> h2[8 waves][512] -> PV partials (8KB)
  __shared__ __align__(16) char lds[81920];
  unsigned* work = (unsigned*)(lds + 65536);

  const int tid  = threadIdx.x;
  const int w    = tid >> 6;      // wave 0..7
  const int lane = tid & 63;
  const int g    = lane >> 4;
  const int lx   = lane & 15;

  // XCD-aware bijective swizzle (4096 % 8 == 0)
  int bid = blockIdx.x;
  int lb  = (bid & 7) * 512 + (bid >> 3);
  int bh  = lb >> 7;
  int b   = bh >> 3, hh = bh & 7;
  int l0  = (lb & 127) << 4;

  const float* Qb = Q + (((size_t)b * 2048 + l0) * 8 + hh) * 64;
  const unsigned short* Khb = Kh + (size_t)bh * 2048 * 64;
  const unsigned short* Vtb = Vt + (size_t)bh * 64 * 2048;

  // zero hist1 (4096 u32)
  {
    uint4 z4 = {0u,0u,0u,0u};
    uint4* p = (uint4*)work;
    p[tid] = z4;
    p[tid + 512] = z4;
  }

  // Q B-frag (col=lx, k=g*8..; two K-halves), scale QS folded (log2-domain scores)
  union FU { f16x8 v; unsigned u[4]; };
  FU qa0, qa1;
  {
    const float* qp = Qb + (size_t)lx * 512 + g * 8;
    float4 a = *(const float4*)(qp);
    float4 c = *(const float4*)(qp + 4);
    qa0.u[0] = pk2(a.x*QS, a.y*QS); qa0.u[1] = pk2(a.z*QS, a.w*QS);
    qa0.u[2] = pk2(c.x*QS, c.y*QS); qa0.u[3] = pk2(c.z*QS, c.w*QS);
    a = *(const float4*)(qp + 32);
    c = *(const float4*)(qp + 36);
    qa1.u[0] = pk2(a.x*QS, a.y*QS); qa1.u[1] = pk2(a.z*QS, a.w*QS);
    qa1.u[2] = pk2(c.x*QS, c.y*QS); qa1.u[3] = pk2(c.z*QS, c.w*QS);
  }
  __syncthreads();

  // ===== QK^T transposed: D[s][q] = mfma(A=K, B=Q); lane holds 4 consecutive s for q=lx =====
  const unsigned swl = ((unsigned)(lx & 7)) << 4;
  const unsigned rot = ((unsigned)lx) << 2;        // hist1 bin rotation for row lx
  const unsigned hinc = (g < 2) ? 1u : 0x10000u;   // g-split counter field
  unsigned* hq = work + lx * 256;
  #pragma unroll 4
  for (int t = 0; t < 16; ++t) {
    int s0 = (t * 8 + w) * 16;
    const unsigned short* kp = Khb + (size_t)(s0 + lx) * 64 + g * 8;
    f16x8 kb0 = *(const f16x8*)(kp);
    f16x8 kb1 = *(const f16x8*)(kp + 32);
    f32x4 acc = {0.f, 0.f, 0.f, 0.f};
    acc = __builtin_amdgcn_mfma_f32_16x16x32_f16(kb0, qa0.v, acc, 0, 0, 0);
    acc = __builtin_amdgcn_mfma_f32_16x16x32_f16(kb1, qa1.v, acc, 0, 0, 0);
    unsigned u0 = pk2(acc[0], acc[1]);
    unsigned u1 = pk2(acc[2], acc[3]);
    uint2 wv = {u0, u1};
    *(uint2*)(lds + lx * 4096 + (((unsigned)(s0 * 2 + g * 8)) ^ swl)) = wv;
    unsigned o20 = ou16x2(u0), o21 = ou16x2(u1);
    atomicAdd(&hq[(((o20 >>  8) & 255u) + rot) & 255u], hinc);
    atomicAdd(&hq[(( o20 >> 24)         + rot) & 255u], hinc);
    atomicAdd(&hq[(((o21 >>  8) & 255u) + rot) & 255u], hinc);
    atomicAdd(&hq[(( o21 >> 24)         + rot) & 255u], hinc);
  }
  __syncthreads();

  const float aw0 = AW[0], aw1 = AW[1], aw2 = AW[2];

  // ===== round 1: rows 2w (lo16) and 2w+1 (hi16) packed into ONE scan =====
  unsigned d0a[2], d1a[2], d2a[2], k0a[2], k1a[2], k2a[2];
  {
    int qa = 2 * w, qb = 2 * w + 1;
    // un-rotate: word (lane+q)&63 of row q's hist holds logical bins 4*lane..4*lane+3
    uint4 hra = ((const uint4*)(work + qa * 256))[(lane + qa) & 63];
    uint4 hrb = ((const uint4*)(work + qb * 256))[(lane + qb) & 63];
    // collapse g-split, then pack rowA|rowB into lo16|hi16
    unsigned px = ((hra.x & 0xFFFFu) + (hra.x >> 16)) | ((((hrb.x & 0xFFFFu) + (hrb.x >> 16))) << 16);
    unsigned py = ((hra.y & 0xFFFFu) + (hra.y >> 16)) | ((((hrb.y & 0xFFFFu) + (hrb.y >> 16))) << 16);
    unsigned pz = ((hra.z & 0xFFFFu) + (hra.z >> 16)) | ((((hrb.z & 0xFFFFu) + (hrb.z >> 16))) << 16);
    unsigned pw = ((hra.w & 0xFFFFu) + (hra.w >> 16)) | ((((hrb.w & 0xFFFFu) + (hrb.w >> 16))) << 16);
    unsigned ptail = suffix64(px + py + pz + pw, lane);
    unsigned ax = px & 0xFFFFu, ay = py & 0xFFFFu, az = pz & 0xFFFFu, aw_ = pw & 0xFFFFu;
    unsigned p0 = pick_digit(ptail & 0xFFFFu, ax, ay, az, aw_, KSEL0, lane);
    unsigned p1 = pick_digit(ptail & 0xFFFFu, ax, ay, az, aw_, KSEL1, lane);
    unsigned p2 = pick_digit(ptail & 0xFFFFu, ax, ay, az, aw_, KSEL2, lane);
    d0a[0] = p0 >> 16; k0a[0] = p0 & 0xFFFFu;
    d1a[0] = p1 >> 16; k1a[0] = p1 & 0xFFFFu;
    d2a[0] = p2 >> 16; k2a[0] = p2 & 0xFFFFu;
    unsigned bx = px >> 16, by = py >> 16, bz = pz >> 16, bw_ = pw >> 16;
    p0 = pick_digit(ptail >> 16, bx, by, bz, bw_, KSEL0, lane);
    p1 = pick_digit(ptail >> 16, bx, by, bz, bw_, KSEL1, lane);
    p2 = pick_digit(ptail >> 16, bx, by, bz, bw_, KSEL2, lane);
    d0a[1] = p0 >> 16; k0a[1] = p0 & 0xFFFFu;
    d1a[1] = p1 >> 16; k1a[1] = p1 & 0xFFFFu;
    d2a[1] = p2 >> 16; k2a[1] = p2 & 0xFFFFu;
  }

  // ===== round 2, fused: count+exp (1 LDS read) -> thresholds -> Z (regs) -> weights (1 LDS write) =====
  unsigned* hw2 = work + w * 512;
  #pragma unroll 1
  for (int rr = 0; rr < 2; ++rr) {
    int q = 2 * w + rr;
    const unsigned swq = ((unsigned)(q & 7)) << 4;
    char* rowp = lds + q * 4096;
    for (int i = lane; i < 512; i += 64) hw2[i] = 0u;
    unsigned D0 = d0a[rr], D1 = d1a[rr], D2 = d2a[rr];

    // P1: count restricted bins (packed D0|D1, D2 at +256) AND keep e=exp2(s-CSH2) in regs
    unsigned ereg[16];
    #pragma unroll
    for (int it = 0; it < 4; ++it) {
      uint4 dv = *(const uint4*)(rowp + (((unsigned)(it * 1024 + lane * 16)) ^ swq));
      unsigned ws[4] = {dv.x, dv.y, dv.z, dv.w};
      #pragma unroll
      for (int p = 0; p < 4; ++p) {
        unsigned uu = ws[p];
        unsigned b0 = uu & 0xFFFFu, b1 = uu >> 16;
        unsigned o2 = ou16x2(uu);
        unsigned hi0 = (o2 >> 8) & 255u, lo0 = o2 & 255u;
        unsigned hi1 = o2 >> 24,         lo1 = (o2 >> 16) & 255u;
        unsigned add0 = (hi0 == D0 ? 1u : 0u) | (hi0 == D1 ? 0x10000u : 0u);
        unsigned add1 = (hi1 == D0 ? 1u : 0u) | (hi1 == D1 ? 0x10000u : 0u);
        if (add0) atomicAdd(&hw2[lo0], add0);
        if (hi0 == D2) atomicAdd(&hw2[256 + lo0], 1u);
        if (add1) atomicAdd(&hw2[lo1], add1);
        if (hi1 == D2) atomicAdd(&hw2[256 + lo1], 1u);
        float e0 = exp2f(h2f(b0) - CSH2);
        float e1 = exp2f(h2f(b1) - CSH2);
        ereg[it * 4 + p] = pk2(e0, e1);
      }
    }
    // thresholds: packed scan covers D0 (lo16) and D1 (hi16) together; D2 separate
    uint4 pkv = ((const uint4*)hw2)[lane];
    uint4 d2v = ((const uint4*)(hw2 + 256))[lane];
    unsigned ptail = suffix64(pkv.x + pkv.y + pkv.z + pkv.w, lane);
    unsigned hx = pkv.x & 0xFFFFu, hy = pkv.y & 0xFFFFu, hz = pkv.z & 0xFFFFu, hw_ = pkv.w & 0xFFFFu;
    unsigned T1o = (D0 << 8) | (pick_digit(ptail & 0xFFFFu, hx, hy, hz, hw_, k0a[rr], lane) >> 16);
    hx = pkv.x >> 16; hy = pkv.y >> 16; hz = pkv.z >> 16; hw_ = pkv.w >> 16;
    unsigned T2o = (D1 << 8) | (pick_digit(ptail >> 16, hx, hy, hz, hw_, k1a[rr], lane) >> 16);
    unsigned t2 = suffix64(d2v.x + d2v.y + d2v.z + d2v.w, lane);
    unsigned T3o = (D2 << 8) | (pick_digit(t2, d2v.x, d2v.y, d2v.z, d2v.w, k2a[rr], lane) >> 16);
    // e-bit thresholds (e>0, monotone in bits)
    unsigned e1b = pk2(exp2f(h2f(ou16_inv(T1o)) - CSH2), 0.f) & 0xFFFFu;
    unsigned e2b = pk2(exp2f(h2f(ou16_inv(T2o)) - CSH2), 0.f) & 0xFFFFu;
    unsigned e3b = pk2(exp2f(h2f(ou16_inv(T3o)) - CSH2), 0.f) & 0xFFFFu;

    // P2: Z from regs, band-bucketed (nested z1 ⊇ z2 ⊇ z3)
    float zbA = 0.f, zbB = 0.f, zbC = 0.f;
    #pragma unroll
    for (int i = 0; i < 16; ++i) {
      unsigned uu = ereg[i];
      unsigned b0 = uu & 0xFFFFu, b1 = uu >> 16;
      float e0 = h2f(b0), e1 = h2f(b1);
      if (b0 >= e1b) zbA += e0; else if (b0 >= e2b) zbB += e0; else if (b0 >= e3b) zbC += e0;
      if (b1 >= e1b) zbA += e1; else if (b1 >= e2b) zbB += e1; else if (b1 >= e3b) zbC += e1;
    }
    #pragma unroll
    for (int off = 1; off < 64; off <<= 1) {
      zbA += __shfl_xor(zbA, off, 64);
      zbB += __shfl_xor(zbB, off, 64);
      zbC += __shfl_xor(zbC, off, 64);
    }
    float z1 = zbA, z2 = zbA + zbB, z3 = z2 + zbC;
    float A3 = aw2 / z3;
    float A2 = aw1 / z2 + A3;
    float A1 = aw0 / z1 + A2;
    unsigned A1b = pk2(A1 * WSC, 0.f) & 0xFFFFu;
    unsigned A2b = pk2(A2 * WSC, 0.f) & 0xFFFFu;
    unsigned A3b = pk2(A3 * WSC, 0.f) & 0xFFFFu;

    // P3: weights from regs, packed fp16 multiply, single LDS write
    #pragma unroll
    for (int it = 0; it < 4; ++it) {
      unsigned no[4];
      #pragma unroll
      for (int p = 0; p < 4; ++p) {
        unsigned uu = ereg[it * 4 + p];
        unsigned b0 = uu & 0xFFFFu, b1 = uu >> 16;
        unsigned c0 = (b0 >= e1b) ? A1b : (b0 >= e2b) ? A2b : (b0 >= e3b) ? A3b : 0u;
        unsigned c1 = (b1 >= e1b) ? A1b : (b1 >= e2b) ? A2b : (b1 >= e3b) ? A3b : 0u;
        unsigned cw = c0 | (c1 << 16);
        __half2 prod = *(__half2*)&uu * *(__half2*)&cw;   // v_pk_mul_f16
        no[p] = *(unsigned*)&prod;
      }
      uint4 nv = {no[0], no[1], no[2], no[3]};
      *(uint4*)(rowp + (((unsigned)(it * 1024 + lane * 16)) ^ swq)) = nv;
    }
  }

  // ===== PV prefetch: issue first 8 Vt loads before the barrier =====
  const int dt = (w >> 1) * 16;
  const int sh = w & 1;
  const unsigned short* vp = Vtb + (size_t)(dt + lx) * 2048 + sh * 1024 + g * 8;
  f16x8 pv0 = *(const f16x8*)(vp);
  f16x8 pv1 = *(const f16x8*)(vp + 32);
  f16x8 pv2 = *(const f16x8*)(vp + 64);
  f16x8 pv3 = *(const f16x8*)(vp + 96);
  f16x8 pv4 = *(const f16x8*)(vp + 128);
  f16x8 pv5 = *(const f16x8*)(vp + 160);
  f16x8 pv6 = *(const f16x8*)(vp + 192);
  f16x8 pv7 = *(const f16x8*)(vp + 224);
  __syncthreads();

  // ===== PV: out^T[d][q] = sum_s Vt[d][s] * w[q][s]; 8 waves = 4 d-tiles x 2 s-halves =====
  f32x4 oacc = {0.f, 0.f, 0.f, 0.f};
  const char* bp = lds + lx * 4096;
  const unsigned sbase = (unsigned)((sh * 1024 + g * 8) * 2);

  __builtin_amdgcn_s_setprio(1);
  oacc = __builtin_amdgcn_mfma_f32_16x16x32_f16(pv0,
           *(const f16x8*)(bp + ((sbase +   0u) ^ swl)), oacc, 0, 0, 0);
  oacc = __builtin_amdgcn_mfma_f32_16x16x32_f16(pv1,
           *(const f16x8*)(bp + ((sbase +  64u) ^ swl)), oacc, 0, 0, 0);
  oacc = __builtin_amdgcn_mfma_f32_16x16x32_f16(pv2,
           *(const f16x8*)(bp + ((sbase + 128u) ^ swl)), oacc, 0, 0, 0);
  oacc = __builtin_amdgcn_mfma_f32_16x16x32_f16(pv3,
           *(const f16x8*)(bp + ((sbase + 192u) ^ swl)), oacc, 0, 0, 0);
  oacc = __builtin_amdgcn_mfma_f32_16x16x32_f16(pv4,
           *(const f16x8*)(bp + ((sbase + 256u) ^ swl)), oacc, 0, 0, 0);
  oacc = __builtin_amdgcn_mfma_f32_16x16x32_f16(pv5,
           *(const f16x8*)(bp + ((sbase + 320u) ^ swl)), oacc, 0, 0, 0);
  oacc = __builtin_amdgcn_mfma_f32_16x16x32_f16(pv6,
           *(const f16x8*)(bp + ((sbase + 384u) ^ swl)), oacc, 0, 0, 0);
  oacc = __builtin_amdgcn_mfma_f32_16x16x32_f16(pv7,
           *(const f16x8*)(bp + ((sbase + 448u) ^ swl)), oacc, 0, 0, 0);

  #pragma unroll 4
  for (int kc = 8; kc < 32; ++kc) {
    f16x8 av = *(const f16x8*)(vp + kc * 32);
    f16x8 bv = *(const f16x8*)(bp + ((sbase + (unsigned)(kc * 64)) ^ swl));
    oacc = __builtin_amdgcn_mfma_f32_16x16x32_f16(av, bv, oacc, 0, 0, 0);
  }
  __builtin_amdgcn_s_setprio(0);

  float* pbuf = (float*)work;   // 8 waves x 256 floats = 8KB
  *(f32x4*)(pbuf + w * 256 + lx * 16 + g * 4) = oacc;
  __syncthreads();
  if (w < 4) {
    const float* pa = pbuf + (2 * w) * 256 + lx * 16 + g * 4;
    float4 ra = *(const float4*)pa;
    float4 rb = *(const float4*)(pa + 256);
    float* op = Out + (((size_t)b * 2048 + l0 + lx) * 8 + hh) * 64 + w * 16 + g * 4;
    float4 ov = { (ra.x + rb.x) * (1.f/WSC), (ra.y + rb.y) * (1.f/WSC),
                  (ra.z + rb.z) * (1.f/WSC), (ra.w + rb.w) * (1.f/WSC) };
    *(float4*)op = ov;
  }
}

extern "C" void kernel_launch(void* const* d_in, const int* in_sizes, int n_in,
                              void* d_out, int out_size, void* d_ws, size_t ws_size,
                              hipStream_t stream) {
  (void)in_sizes; (void)n_in; (void)out_size; (void)ws_size;
  const float* Q  = (const float*)d_in[0];
  const float* K  = (const float*)d_in[1];
  const float* V  = (const float*)d_in[2];
  const float* AW = (const float*)d_in[3];
  unsigned short* Kh = (unsigned short*)d_ws;                    // 8.4 MB
  unsigned short* Vt = (unsigned short*)((char*)d_ws + 8388608); // 8.4 MB
  prep_kv<<<dim3(2560), dim3(256), 0, stream>>>(K, V, Kh, Vt);
  nma_kernel<<<dim3(4096), dim3(512), 0, stream>>>(Q, Kh, Vt, AW, (float*)d_out);
}